// Round 7
// baseline (392.452 us; speedup 1.0000x reference)
//
#include <hip/hip_runtime.h>

#define BATCH 16
#define NPTS 1024
#define CIN 16
#define NODES (BATCH*NPTS)      // 16384
#define KNN 10
#define EDGES (NODES*KNN)       // 163840
#define JCH 8                   // j-chunks for KNN
#define JLEN (NPTS/JCH)         // 128

typedef unsigned short ushort_t;
typedef __attribute__((ext_vector_type(8))) short bf16x8;
typedef __attribute__((ext_vector_type(8))) unsigned short u16x8;
typedef __attribute__((ext_vector_type(4))) float f32x4;
typedef __attribute__((ext_vector_type(2))) float f32x2;

__device__ __forceinline__ int uclamp(int v, int hi) {
    return ((unsigned)v > (unsigned)hi) ? hi : v;
}
__device__ __forceinline__ float bf2f(ushort_t u) {
    union { unsigned int i; float f; } v; v.i = ((unsigned int)u) << 16; return v.f;
}
__device__ __forceinline__ ushort_t f2bf(float f) {
    union { float f; unsigned int i; } v; v.f = f;
    unsigned int r = (v.i + 0x7fffu + ((v.i >> 16) & 1u)) >> 16;
    return (ushort_t)r;
}

// ---------------- cast layer-1..3 weights f32 -> bf16 (229376 elems) ----------------
// fold-ins: 0.5*|x_j|^2 per point (KNN distance seed) + zero cnt/cur (for fused counting)
__global__ __launch_bounds__(256) void cast_weights(const float* __restrict__ s0,
                                                    const float* __restrict__ s1,
                                                    const float* __restrict__ s2,
                                                    const float* __restrict__ s3,
                                                    const float* __restrict__ s4,
                                                    const float* __restrict__ s5,
                                                    ushort_t* __restrict__ dst,
                                                    const float* __restrict__ xf,
                                                    float* __restrict__ sqh,
                                                    int* __restrict__ cntz) {
    int t = blockIdx.x * 256 + threadIdx.x;   // 896 blocks
    if (t < NODES) {
        const float4* xp = (const float4*)(xf + (size_t)t * 16);
        float4 a = xp[0], b = xp[1], c = xp[2], d = xp[3];
        float s = a.x*a.x + a.y*a.y + a.z*a.z + a.w*a.w
                + b.x*b.x + b.y*b.y + b.z*b.z + b.w*b.w
                + c.x*c.x + c.y*c.y + c.z*c.z + c.w*c.w
                + d.x*d.x + d.y*d.y + d.z*d.z + d.w*d.w;
        sqh[t] = 0.5f * s;
    }
    if (t < 2 * NODES) cntz[t] = 0;           // cnt (16384) + cur (16384), contiguous
    const float* s; int off;
    if      (t <  32768) { s = s0; off = 0; }
    else if (t <  65536) { s = s1; off = 32768; }
    else if (t < 131072) { s = s2; off = 65536; }
    else if (t < 196608) { s = s3; off = 131072; }
    else if (t < 212992) { s = s4; off = 196608; }
    else                 { s = s5; off = 212992; }
    dst[t] = f2bf(s[t - off]);
}

// ---------------- KNN phase A: per-(i, j-chunk) top-10 ----------------
__global__ __launch_bounds__(128, 4) void knn_partial(const float* __restrict__ xf,
                                                      const float* __restrict__ sqh,
                                                      float* __restrict__ pd,
                                                      ushort_t* __restrict__ pi_) {
    int jc = blockIdx.x, ic = blockIdx.y, b = blockIdx.z;
    int tid = threadIdx.x;                    // 0..127
    int i_local = (ic << 7) | tid;
    const float* xbp = xf + (size_t)b * NPTS * CIN;
    const float* sqb = sqh + b * NPTS;

    f32x2 nxi[8];
    {
        const f32x2* xip = (const f32x2*)(xbp + (size_t)i_local * 16);
#pragma unroll
        for (int q = 0; q < 8; ++q) nxi[q] = -xip[q];
    }

    int jbase = jc * JLEN;
    const float* yb = xbp + (size_t)jbase * 16;   // wave-uniform base

    float bd[10]; int bi[10];
#pragma unroll
    for (int r = 0; r < 10; ++r) { bd[r] = 3.0e38f; bi[r] = 0; }

#pragma unroll 4
    for (int jl = 0; jl < JLEN; ++jl) {
        const f32x2* y2 = (const f32x2*)(yb + jl * 16);   // uniform -> s_load
        f32x2 acc2 = {sqb[jbase + jl], 0.0f};             // uniform scalar seed
#pragma unroll
        for (int d = 0; d < 8; ++d) acc2 = __builtin_elementwise_fma(nxi[d], y2[d], acc2);
        float dist = acc2.x + acc2.y;
        int j = jbase + jl;
        float c = (j != i_local) ? dist : 3.0e38f;
        bool m[10];
#pragma unroll
        for (int k = 0; k < 10; ++k) m[k] = c < bd[k];
        // in-place descending shift-insert: level k reads only pre-update k-1 state
#pragma unroll
        for (int k = 9; k >= 1; --k) {
            int t = m[k-1] ? bi[k-1] : j;
            bi[k] = m[k] ? t : bi[k];
            bd[k] = __builtin_amdgcn_fmed3f(c, bd[k-1], bd[k]);
        }
        bi[0] = m[0] ? j : bi[0];
        bd[0] = fminf(c, bd[0]);
    }
    size_t base = ((size_t)(b * NPTS + i_local) * JCH + jc) * 10;
#pragma unroll
    for (int r = 0; r < 10; ++r) { pd[base + r] = bd[r]; pi_[base + r] = (ushort_t)bi[r]; }
}

// ---------------- KNN phase B: lane-parallel merge, 8 lanes per node ----------------
__global__ __launch_bounds__(256) void knn_merge(const float* __restrict__ pd,
                                                 const ushort_t* __restrict__ pi_,
                                                 int* __restrict__ nbors,
                                                 int* __restrict__ cnt) {
    int tid = blockIdx.x * 256 + threadIdx.x;     // 0..131071
    int node = tid >> 3;                          // 0..16383
    int sub  = tid & 7;                           // list index (jc)
    int b = node >> 10, i = node & 1023;
    int lane = threadIdx.x & 63;

    size_t base = ((size_t)node * JCH + sub) * 10;
    float d[11]; int id[10];
    {   // bulk-load my sorted list: coalesced (lanes cover contiguous region)
        const float2* dp = (const float2*)(pd + base);
        const unsigned int* ip = (const unsigned int*)(pi_ + base);  // 20B, 4B-aligned
#pragma unroll
        for (int q = 0; q < 5; ++q) {
            float2 dv = dp[q];
            unsigned int iv = ip[q];
            d[2*q] = dv.x; d[2*q+1] = dv.y;
            id[2*q] = (int)(iv & 0xffffu); id[2*q+1] = (int)(iv >> 16);
        }
        d[10] = 3.0e38f;
    }

    int res[10];
#pragma unroll
    for (int r = 0; r < 10; ++r) {
        float hd = d[0]; int hl = sub;
        // min over the 8-lane group (xor masks 1,2,4 stay in-group)
#pragma unroll
        for (int mk = 1; mk <= 4; mk <<= 1) {
            float od = __shfl_xor(hd, mk, 64);
            int   ol = __shfl_xor(hl, mk, 64);
            bool take = (od < hd) || (od == hd && ol < hl);
            hd = take ? od : hd;
            hl = take ? ol : hl;
        }
        // fetch winner's head index
        int src = (lane & 56) | hl;
        res[r] = __shfl(id[0], src, 64);
        // winner advances its list (predicated shift)
        bool win = (sub == hl);
#pragma unroll
        for (int k = 0; k < 9; ++k) {
            d[k]  = win ? d[k+1]  : d[k];
            id[k] = win ? id[k+1] : id[k];
        }
        d[9] = win ? d[10] : d[9];
    }

    if (sub == 0) {
        int gi = b * NPTS + i;
#pragma unroll
        for (int r = 0; r < 10; ++r) {
            int gdst = b * NPTS + uclamp(res[r], NPTS - 1);
            nbors[gi * KNN + r] = gdst;
            atomicAdd(&cnt[gdst], 1);
        }
    }
}

// ---------------- reverse-CSR build ----------------
__global__ __launch_bounds__(256) void scan_kernel(const int* __restrict__ cnt,
                                                   int* __restrict__ rs) {
    __shared__ int part[256];
    int t = threadIdx.x;
    int base = t << 6;
    int4 v[16];
    const int4* cp = (const int4*)(cnt + base);
#pragma unroll
    for (int q = 0; q < 16; ++q) v[q] = cp[q];
    int s = 0;
#pragma unroll
    for (int q = 0; q < 16; ++q) s += v[q].x + v[q].y + v[q].z + v[q].w;
    part[t] = s;
    __syncthreads();
    for (int off = 1; off < 256; off <<= 1) {
        int vv = (t >= off) ? part[t - off] : 0;
        __syncthreads();
        part[t] += vv;
        __syncthreads();
    }
    int run = part[t] - s;
    int4* rp = (int4*)(rs + base);
#pragma unroll
    for (int q = 0; q < 16; ++q) {
        int4 o;
        o.x = run; run += v[q].x;
        o.y = run; run += v[q].y;
        o.z = run; run += v[q].z;
        o.w = run; run += v[q].w;
        rp[q] = o;
    }
    if (t == 255) rs[NODES] = run;
}

__global__ __launch_bounds__(256) void fill_kernel(const int* __restrict__ nbors,
                                                   const int* __restrict__ rs,
                                                   int* __restrict__ cur,
                                                   int* __restrict__ esrc) {
    int e = blockIdx.x * 256 + threadIdx.x;
    if (e < EDGES) {
        int dst = uclamp(nbors[e], NODES - 1);
        int src = e / 10;
        int pos = atomicAdd(&cur[dst], 1);
        esrc[uclamp(rs[dst] + pos, EDGES - 1)] = src;
    }
}

// ---------------- layer-0 GEMM (f32 vector, K=16) + fused neighbor-agg, bf16 out -----
__global__ __launch_bounds__(256) void gemm_layer0(const float* __restrict__ A1,
                                                   const int* __restrict__ rs,
                                                   const int* __restrict__ esrc,
                                                   const float* __restrict__ W1,
                                                   const float* __restrict__ W2,
                                                   const float* __restrict__ bias,
                                                   ushort_t* __restrict__ Out,
                                                   int Ndim) {
    __shared__ float As1[16 * 64], As2[16 * 64], Bs1[16 * 64], Bs2[16 * 64];
    int tid = threadIdx.x;
    int m0 = blockIdx.y * 64;
    int n0 = blockIdx.x * 64;
    int tx = tid & 15, ty = tid >> 4;
    int lr = tid >> 2;
    int lc = (tid & 3) << 2;
    float acc[4][4] = {};

    {   // stage x (transposed) and both weight tiles
        float4 a = *(const float4*)(A1 + (size_t)(m0 + lr) * 16 + lc);
        As1[(lc + 0) * 64 + lr] = a.x; As1[(lc + 1) * 64 + lr] = a.y;
        As1[(lc + 2) * 64 + lr] = a.z; As1[(lc + 3) * 64 + lr] = a.w;
        float4 w1 = *(const float4*)(W1 + (size_t)(n0 + lr) * 16 + lc);
        Bs1[(lc + 0) * 64 + lr] = w1.x; Bs1[(lc + 1) * 64 + lr] = w1.y;
        Bs1[(lc + 2) * 64 + lr] = w1.z; Bs1[(lc + 3) * 64 + lr] = w1.w;
        float4 w2 = *(const float4*)(W2 + (size_t)(n0 + lr) * 16 + lc);
        Bs2[(lc + 0) * 64 + lr] = w2.x; Bs2[(lc + 1) * 64 + lr] = w2.y;
        Bs2[(lc + 2) * 64 + lr] = w2.z; Bs2[(lc + 3) * 64 + lr] = w2.w;
    }
    {   // fused agg: 4 threads per row, 4 channels each
        int r = tid >> 2;
        int c4 = (tid & 3) << 2;
        int n = m0 + r;
        int e1 = uclamp(rs[n + 1], EDGES);
        int e0 = uclamp(rs[n], e1);
        float4 acc4 = {0.f, 0.f, 0.f, 0.f};
        for (int e = e0; e < e1; ++e) {
            int s = uclamp(esrc[e], NODES - 1);
            float4 v = *(const float4*)(A1 + (size_t)s * 16 + c4);
            acc4.x += v.x; acc4.y += v.y; acc4.z += v.z; acc4.w += v.w;
        }
        As2[(c4 + 0) * 64 + r] = acc4.x; As2[(c4 + 1) * 64 + r] = acc4.y;
        As2[(c4 + 2) * 64 + r] = acc4.z; As2[(c4 + 3) * 64 + r] = acc4.w;
    }
    __syncthreads();
#pragma unroll
    for (int k = 0; k < 16; ++k) {
        float4 a1 = *(const float4*)(As1 + k * 64 + (ty << 2));
        float4 a2 = *(const float4*)(As2 + k * 64 + (ty << 2));
        float4 b1 = *(const float4*)(Bs1 + k * 64 + (tx << 2));
        float4 b2 = *(const float4*)(Bs2 + k * 64 + (tx << 2));
        float av1[4] = {a1.x, a1.y, a1.z, a1.w};
        float av2[4] = {a2.x, a2.y, a2.z, a2.w};
        float bv1[4] = {b1.x, b1.y, b1.z, b1.w};
        float bv2[4] = {b2.x, b2.y, b2.z, b2.w};
#pragma unroll
        for (int u = 0; u < 4; ++u)
#pragma unroll
            for (int v = 0; v < 4; ++v)
                acc[u][v] += av1[u] * bv1[v] + av2[u] * bv2[v];
    }
    float bv[4];
#pragma unroll
    for (int v = 0; v < 4; ++v) bv[v] = bias[n0 + (tx << 2) + v];
#pragma unroll
    for (int u = 0; u < 4; ++u) {
        int m = m0 + (ty << 2) + u;
        ushort4 o;
        o.x = f2bf(fmaxf(acc[u][0] + bv[0], 0.f));
        o.y = f2bf(fmaxf(acc[u][1] + bv[1], 0.f));
        o.z = f2bf(fmaxf(acc[u][2] + bv[2], 0.f));
        o.w = f2bf(fmaxf(acc[u][3] + bv[3], 0.f));
        *(ushort4*)(Out + (size_t)m * Ndim + n0 + (tx << 2)) = o;
    }
}

// ---------------- fused agg + MFMA dual-GEMM (layers 1-2), N=256 ----------------
// grid dim3(NSPL, 256) x 512. Block: rows m0..m0+63, cols [bx*CPB, bx*CPB+CPB).
// NSPL>1 duplicates the gather (bit-identical) to raise blocks/CU -> more outstanding
// misses during the latency-bound gather. 2-way edge unroll doubles loads in flight.
// Wave: row-tile wave>>1, col-half wave&1 (CPB/2 cols, NTW=CPB/32 dual-MFMA tiles).
template<int KD, int NSPL>
__global__ __launch_bounds__(512) void gemm_fused(const ushort_t* __restrict__ hin,
                                                  const int* __restrict__ rs,
                                                  const int* __restrict__ esrc,
                                                  const ushort_t* __restrict__ W1,
                                                  const ushort_t* __restrict__ W2,
                                                  const float* __restrict__ bias,
                                                  ushort_t* __restrict__ outp) {
    constexpr int CPB = 256 / NSPL;       // cols per block
    constexpr int NTW = CPB / 32;         // 16-col tiles per wave (per col-half)
    __shared__ ushort_t As2[64 * KD];     // 16 KB (KD=128) / 32 KB (KD=256)
    int tid = threadIdx.x;
    int m0 = blockIdx.y * 64;

    {   // gather-aggregate: 8 threads/row, KD/8 channels each, 2-way edge unroll
        int r = tid >> 3;
        int ch0 = (tid & 7) * (KD / 8);
        int n = m0 + r;
        int e1 = uclamp(rs[n + 1], EDGES);
        int e0 = uclamp(rs[n], e1);
        constexpr int NV = KD / 64;       // u16x8 vectors per thread (2 or 4)
        float a[KD / 8];
#pragma unroll
        for (int k = 0; k < KD / 8; ++k) a[k] = 0.f;
        int e = e0;
        for (; e + 2 <= e1; e += 2) {
            int s0 = uclamp(esrc[e], NODES - 1);
            int s1 = uclamp(esrc[e + 1], NODES - 1);
            const u16x8* vp0 = (const u16x8*)(hin + (size_t)s0 * KD + ch0);
            const u16x8* vp1 = (const u16x8*)(hin + (size_t)s1 * KD + ch0);
            u16x8 v0[NV], v1[NV];
#pragma unroll
            for (int q = 0; q < NV; ++q) { v0[q] = vp0[q]; v1[q] = vp1[q]; }
#pragma unroll
            for (int q = 0; q < NV; ++q)
#pragma unroll
                for (int k = 0; k < 8; ++k)
                    a[q * 8 + k] += bf2f(v0[q][k]) + bf2f(v1[q][k]);
        }
        if (e < e1) {
            int s0 = uclamp(esrc[e], NODES - 1);
            const u16x8* vp0 = (const u16x8*)(hin + (size_t)s0 * KD + ch0);
#pragma unroll
            for (int q = 0; q < NV; ++q) {
                u16x8 v = vp0[q];
#pragma unroll
                for (int k = 0; k < 8; ++k) a[q * 8 + k] += bf2f(v[k]);
            }
        }
#pragma unroll
        for (int q = 0; q < NV; ++q) {
            u16x8 o;
#pragma unroll
            for (int k = 0; k < 8; ++k) o[k] = f2bf(a[q * 8 + k]);
            unsigned byte = ((unsigned)(r * KD + ch0 + q * 8) * 2u)
                          ^ (((unsigned)(r & 7)) << 4);
            *(u16x8*)((char*)As2 + byte) = o;
        }
    }
    __syncthreads();

    int wave = tid >> 6, lane = tid & 63;
    int quad = lane >> 4, l16 = lane & 15;
    int mt = wave >> 1, nh = wave & 1;
    int ms = m0 + mt * 16;
    int nbase = blockIdx.x * CPB + nh * (CPB / 2);
    int lrow = mt * 16 + l16;

    f32x4 acc[NTW] = {};
    const ushort_t* a1p = hin + (size_t)(ms + l16) * KD + quad * 8;
    const ushort_t* w1p = W1 + (size_t)(nbase + l16) * KD + quad * 8;
    const ushort_t* w2p = W2 + (size_t)(nbase + l16) * KD + quad * 8;
    size_t wstride = (size_t)16 * KD;

#pragma unroll
    for (int k0 = 0; k0 < KD; k0 += 32) {
        bf16x8 a1 = *(const bf16x8*)(a1p + k0);
        unsigned byte = ((unsigned)(lrow * KD + quad * 8 + k0) * 2u)
                      ^ (((unsigned)(lrow & 7)) << 4);
        bf16x8 a2 = *(const bf16x8*)((const char*)As2 + byte);
#pragma unroll
        for (int nt = 0; nt < NTW; ++nt) {
            bf16x8 u = *(const bf16x8*)(w1p + (size_t)nt * wstride + k0);
            bf16x8 v = *(const bf16x8*)(w2p + (size_t)nt * wstride + k0);
            acc[nt] = __builtin_amdgcn_mfma_f32_16x16x32_bf16(a1, u, acc[nt], 0, 0, 0);
            acc[nt] = __builtin_amdgcn_mfma_f32_16x16x32_bf16(a2, v, acc[nt], 0, 0, 0);
        }
    }
#pragma unroll
    for (int nt = 0; nt < NTW; ++nt) {
        int n = nbase + nt * 16 + l16;
        float bb = bias[n];
#pragma unroll
        for (int r2 = 0; r2 < 4; ++r2) {
            float v = fmaxf(acc[nt][r2] + bb, 0.f);
            int m = ms + quad * 4 + r2;
            outp[(size_t)m * 256 + n] = f2bf(v);
        }
    }
}

// ---------------- layer-3 GEMM: shared-A, two f32 outputs (P=h.Wrel^T, Q=h.Wroot^T) ---
__global__ __launch_bounds__(256) void gemm_l3(const ushort_t* __restrict__ A,
                                               const ushort_t* __restrict__ Wroot,
                                               const ushort_t* __restrict__ Wrel,
                                               float* __restrict__ Q3,
                                               float* __restrict__ P3,
                                               int Kdim) {
    int tid = threadIdx.x;
    int wave = tid >> 6, lane = tid & 63;
    int quad = lane >> 4, l16 = lane & 15;
    int ms = blockIdx.y * 64 + wave * 16;

    f32x4 accQ[4] = {{0,0,0,0},{0,0,0,0},{0,0,0,0},{0,0,0,0}};
    f32x4 accP[4] = {{0,0,0,0},{0,0,0,0},{0,0,0,0},{0,0,0,0}};
    const ushort_t* ap  = A + (size_t)(ms + l16) * Kdim + quad * 8;
    const ushort_t* wrp = Wroot + (size_t)l16 * Kdim + quad * 8;
    const ushort_t* wep = Wrel  + (size_t)l16 * Kdim + quad * 8;
    size_t wstride = (size_t)16 * Kdim;

    for (int k0 = 0; k0 < Kdim; k0 += 32) {
        bf16x8 a = *(const bf16x8*)(ap + k0);
#pragma unroll
        for (int nt = 0; nt < 4; ++nt) {
            bf16x8 u = *(const bf16x8*)(wrp + (size_t)nt * wstride + k0);
            bf16x8 v = *(const bf16x8*)(wep + (size_t)nt * wstride + k0);
            accQ[nt] = __builtin_amdgcn_mfma_f32_16x16x32_bf16(a, u, accQ[nt], 0, 0, 0);
            accP[nt] = __builtin_amdgcn_mfma_f32_16x16x32_bf16(a, v, accP[nt], 0, 0, 0);
        }
    }
#pragma unroll
    for (int nt = 0; nt < 4; ++nt) {
        int n = nt * 16 + l16;
#pragma unroll
        for (int r = 0; r < 4; ++r) {
            int m = ms + quad * 4 + r;
            Q3[(size_t)m * 64 + n] = accQ[nt][r];
            P3[(size_t)m * 64 + n] = accP[nt][r];
        }
    }
}

// ---------------- layer-3 aggregate + bias + hi/lo split ----------------
__global__ __launch_bounds__(256) void agg_final(const float* __restrict__ P3,
                                                 const float* __restrict__ Q3,
                                                 const float* __restrict__ bias,
                                                 const int* __restrict__ rs,
                                                 const int* __restrict__ esrc,
                                                 ushort_t* __restrict__ h4hi,
                                                 ushort_t* __restrict__ h4lo) {
    int gid = blockIdx.x * 256 + threadIdx.x;     // 0..262143
    int n = gid >> 4;
    int c = (gid & 15) << 2;
    int e1 = uclamp(rs[n + 1], EDGES);
    int e0 = uclamp(rs[n], e1);
    float4 acc = {0.f, 0.f, 0.f, 0.f};
    for (int e = e0; e < e1; ++e) {
        int s = uclamp(esrc[e], NODES - 1);
        float4 v = *(const float4*)(P3 + (size_t)s * 64 + c);
        acc.x += v.x; acc.y += v.y; acc.z += v.z; acc.w += v.w;
    }
    float4 q = *(const float4*)(Q3 + (size_t)n * 64 + c);
    float4 bb = *(const float4*)(bias + c);
    float v0 = acc.x + q.x + bb.x;
    float v1 = acc.y + q.y + bb.y;
    float v2 = acc.z + q.z + bb.z;
    float v3 = acc.w + q.w + bb.w;
    ushort4 hi, lo;
    hi.x = f2bf(v0); lo.x = f2bf(v0 - bf2f(hi.x));
    hi.y = f2bf(v1); lo.y = f2bf(v1 - bf2f(hi.y));
    hi.z = f2bf(v2); lo.z = f2bf(v2 - bf2f(hi.z));
    hi.w = f2bf(v3); lo.w = f2bf(v3 - bf2f(hi.w));
    *(ushort4*)(h4hi + (size_t)n * 64 + c) = hi;
    *(ushort4*)(h4lo + (size_t)n * 64 + c) = lo;
}

// ---------------- final Gram via split-bf16 MFMA: D = H·H^T, f32 out ----------------
__global__ __launch_bounds__(256) void final_mfma(const ushort_t* __restrict__ Hhi,
                                                  const ushort_t* __restrict__ Hlo,
                                                  float* __restrict__ out) {
    int tid = threadIdx.x;
    int wave = tid >> 6, lane = tid & 63;
    int quad = lane >> 4, l16 = lane & 15;
    int bz = blockIdx.z;
    int nbase = blockIdx.y * 64 + wave * 16;
    int m0 = blockIdx.x * 64;
    const ushort_t* Hbh = Hhi + (size_t)bz * NPTS * 64;
    const ushort_t* Hbl = Hlo + (size_t)bz * NPTS * 64;

    f32x4 acc[4] = {{0.f,0.f,0.f,0.f},{0.f,0.f,0.f,0.f},{0.f,0.f,0.f,0.f},{0.f,0.f,0.f,0.f}};
    const ushort_t* aph = Hbh + (size_t)(nbase + l16) * 64 + quad * 8;
    const ushort_t* apl = Hbl + (size_t)(nbase + l16) * 64 + quad * 8;
    const ushort_t* bph = Hbh + (size_t)(m0 + l16) * 64 + quad * 8;
    const ushort_t* bpl = Hbl + (size_t)(m0 + l16) * 64 + quad * 8;

#pragma unroll
    for (int k0 = 0; k0 < 64; k0 += 32) {
        bf16x8 ah = *(const bf16x8*)(aph + k0);
        bf16x8 al = *(const bf16x8*)(apl + k0);
#pragma unroll
        for (int nt = 0; nt < 4; ++nt) {
            bf16x8 bh = *(const bf16x8*)(bph + (size_t)nt * 16 * 64 + k0);
            bf16x8 bl = *(const bf16x8*)(bpl + (size_t)nt * 16 * 64 + k0);
            acc[nt] = __builtin_amdgcn_mfma_f32_16x16x32_bf16(ah, bh, acc[nt], 0, 0, 0);
            acc[nt] = __builtin_amdgcn_mfma_f32_16x16x32_bf16(ah, bl, acc[nt], 0, 0, 0);
            acc[nt] = __builtin_amdgcn_mfma_f32_16x16x32_bf16(al, bh, acc[nt], 0, 0, 0);
        }
    }
#pragma unroll
    for (int nt = 0; nt < 4; ++nt) {
#pragma unroll
        for (int r = 0; r < 4; ++r) {
            int n = nbase + quad * 4 + r;
            int m = m0 + nt * 16 + l16;
            out[((size_t)(bz * NPTS + n)) * NPTS + m] = acc[nt][r];
        }
    }
}

// ---------------- launch ----------------
extern "C" void kernel_launch(void* const* d_in, const int* in_sizes, int n_in,
                              void* d_out, int out_size, void* d_ws, size_t ws_size,
                              hipStream_t stream) {
    const float* x = (const float*)d_in[0];
    const float* W[12];
    for (int i = 0; i < 12; ++i) W[i] = (const float*)d_in[1 + i];
    float* out = (float*)d_out;

    // d_ws (~5.5 MB): h4 hi/lo + graph structs
    char* w = (char*)d_ws;
    ushort_t* h4hi = (ushort_t*)w; w += (size_t)NODES * 64 * 2;     // 2 MB
    ushort_t* h4lo = (ushort_t*)w; w += (size_t)NODES * 64 * 2;     // 2 MB
    int* nbors  = (int*)w;    w += (size_t)EDGES * 4;               // 640 KB
    int* cnt    = (int*)w;    w += (size_t)NODES * 4;               // 64 KB
    int* cur    = (int*)w;    w += (size_t)NODES * 4;               // 64 KB (contiguous after cnt)
    int* rs     = (int*)w;    w += (size_t)(NODES + 1) * 4 + 12;    // 64 KB
    int* esrc   = (int*)w;    w += (size_t)EDGES * 4;               // 640 KB

    // scratch inside d_out (64 MB, fully overwritten by final_mfma).
    char* ob = (char*)d_out;
    ushort_t* wb    = (ushort_t*)(ob + 0);                   // 448 KB bf16 weights
    float*    sqh   = (float*)   (ob + (size_t)512*1024);    // 64 KB (0.5*|x|^2)
    float*    pd    = (float*)   (ob + (size_t) 1u*1048576); // 5 MiB [node][jc(8)][10] f32
    ushort_t* pi_   = (ushort_t*)(ob + (size_t) 6u*1048576); // 2.5 MiB
    ushort_t* h1b   = (ushort_t*)(ob + (size_t) 1u*1048576); // 4 MB  (aliases pd)
    ushort_t* h2b   = (ushort_t*)(ob + (size_t)13u*1048576); // 8 MB
    ushort_t* h3b   = (ushort_t*)(ob + (size_t)21u*1048576); // 8 MB
    float*    P3    = (float*)   (ob + (size_t)29u*1048576); // 4 MB f32 (h3.Wrel^T)
    float*    Q3    = (float*)   (ob + (size_t)33u*1048576); // 4 MB f32 (h3.Wroot^T)

    cast_weights<<<896, 256, 0, stream>>>(W[3], W[4], W[6], W[7], W[9], W[10], wb, x, sqh, cnt);
    knn_partial<<<dim3(JCH, 8, BATCH), 128, 0, stream>>>(x, sqh, pd, pi_);
    knn_merge<<<512, 256, 0, stream>>>(pd, pi_, nbors, cnt);   // fused in-degree count
    scan_kernel<<<1, 256, 0, stream>>>(cnt, rs);
    fill_kernel<<<EDGES / 256, 256, 0, stream>>>(nbors, rs, cur, esrc);

    // layer 0: K=16, N=128, f32 compute, fused neighbor-agg, bf16 out
    gemm_layer0<<<dim3(2, 256), 256, 0, stream>>>(x, rs, esrc, W[0], W[1], W[2], h1b, 128);
    // layer 1: K=128, N=256, fused agg + MFMA, N-split 2 (2 blocks/CU)
    gemm_fused<128, 2><<<dim3(2, 256), 512, 0, stream>>>(h1b, rs, esrc, wb, wb + 32768,
                                                         W[5], h2b);
    // layer 2: K=256, N=256, fused agg + MFMA, N-split 4 (4 blocks/CU)
    gemm_fused<256, 4><<<dim3(4, 256), 512, 0, stream>>>(h2b, rs, esrc, wb + 65536,
                                                         wb + 131072, W[8], h3b);
    // layer 3: project first (shared-A dual GEMM, f32 out), then aggregate 64-dim rows
    gemm_l3<<<dim3(1, 256), 256, 0, stream>>>(h3b, wb + 196608, wb + 212992, Q3, P3, 256);
    agg_final<<<1024, 256, 0, stream>>>(P3, Q3, W[11], rs, esrc, h4hi, h4lo);

    final_mfma<<<dim3(16, 16, 16), 256, 0, stream>>>(h4hi, h4lo, out);
}

// Round 8
// 309.531 us; speedup vs baseline: 1.2679x; 1.2679x over previous
//
#include <hip/hip_runtime.h>

#define BATCH 16
#define NPTS 1024
#define CIN 16
#define NODES (BATCH*NPTS)      // 16384
#define KNN 10
#define EDGES (NODES*KNN)       // 163840
#define JCH 8                   // j-chunks for KNN
#define JLEN (NPTS/JCH)         // 128

typedef unsigned short ushort_t;
typedef __attribute__((ext_vector_type(8))) short bf16x8;
typedef __attribute__((ext_vector_type(8))) unsigned short u16x8;
typedef __attribute__((ext_vector_type(4))) float f32x4;
typedef __attribute__((ext_vector_type(2))) float f32x2;

__device__ __forceinline__ int uclamp(int v, int hi) {
    return ((unsigned)v > (unsigned)hi) ? hi : v;
}
__device__ __forceinline__ float bf2f(ushort_t u) {
    union { unsigned int i; float f; } v; v.i = ((unsigned int)u) << 16; return v.f;
}
__device__ __forceinline__ ushort_t f2bf(float f) {
    union { float f; unsigned int i; } v; v.f = f;
    unsigned int r = (v.i + 0x7fffu + ((v.i >> 16) & 1u)) >> 16;
    return (ushort_t)r;
}

// ---------------- cast layer-1..3 weights f32 -> bf16 (229376 elems) ----------------
__global__ __launch_bounds__(256) void cast_weights(const float* __restrict__ s0,
                                                    const float* __restrict__ s1,
                                                    const float* __restrict__ s2,
                                                    const float* __restrict__ s3,
                                                    const float* __restrict__ s4,
                                                    const float* __restrict__ s5,
                                                    ushort_t* __restrict__ dst,
                                                    const float* __restrict__ xf,
                                                    float* __restrict__ sqh,
                                                    int* __restrict__ cntz) {
    int t = blockIdx.x * 256 + threadIdx.x;   // 896 blocks
    if (t < NODES) {
        const float4* xp = (const float4*)(xf + (size_t)t * 16);
        float4 a = xp[0], b = xp[1], c = xp[2], d = xp[3];
        float s = a.x*a.x + a.y*a.y + a.z*a.z + a.w*a.w
                + b.x*b.x + b.y*b.y + b.z*b.z + b.w*b.w
                + c.x*c.x + c.y*c.y + c.z*c.z + c.w*c.w
                + d.x*d.x + d.y*d.y + d.z*d.z + d.w*d.w;
        sqh[t] = 0.5f * s;
    }
    if (t < 2 * NODES) cntz[t] = 0;           // cnt (16384) + cur (16384), contiguous
    const float* s; int off;
    if      (t <  32768) { s = s0; off = 0; }
    else if (t <  65536) { s = s1; off = 32768; }
    else if (t < 131072) { s = s2; off = 65536; }
    else if (t < 196608) { s = s3; off = 131072; }
    else if (t < 212992) { s = s4; off = 196608; }
    else                 { s = s5; off = 212992; }
    dst[t] = f2bf(s[t - off]);
}

// ---------------- KNN phase A: per-(i, j-chunk) top-10 ----------------
__global__ __launch_bounds__(128, 4) void knn_partial(const float* __restrict__ xf,
                                                      const float* __restrict__ sqh,
                                                      float* __restrict__ pd,
                                                      ushort_t* __restrict__ pi_) {
    int jc = blockIdx.x, ic = blockIdx.y, b = blockIdx.z;
    int tid = threadIdx.x;                    // 0..127
    int i_local = (ic << 7) | tid;
    const float* xbp = xf + (size_t)b * NPTS * CIN;
    const float* sqb = sqh + b * NPTS;

    f32x2 nxi[8];
    {
        const f32x2* xip = (const f32x2*)(xbp + (size_t)i_local * 16);
#pragma unroll
        for (int q = 0; q < 8; ++q) nxi[q] = -xip[q];
    }

    int jbase = jc * JLEN;
    const float* yb = xbp + (size_t)jbase * 16;   // wave-uniform base

    float bd[10]; int bi[10];
#pragma unroll
    for (int r = 0; r < 10; ++r) { bd[r] = 3.0e38f; bi[r] = 0; }

#pragma unroll 4
    for (int jl = 0; jl < JLEN; ++jl) {
        const f32x2* y2 = (const f32x2*)(yb + jl * 16);   // uniform -> s_load
        f32x2 acc2 = {sqb[jbase + jl], 0.0f};             // uniform scalar seed
#pragma unroll
        for (int d = 0; d < 8; ++d) acc2 = __builtin_elementwise_fma(nxi[d], y2[d], acc2);
        float dist = acc2.x + acc2.y;
        int j = jbase + jl;
        float c = (j != i_local) ? dist : 3.0e38f;
        bool m[10];
#pragma unroll
        for (int k = 0; k < 10; ++k) m[k] = c < bd[k];
#pragma unroll
        for (int k = 9; k >= 1; --k) {
            int t = m[k-1] ? bi[k-1] : j;
            bi[k] = m[k] ? t : bi[k];
            bd[k] = __builtin_amdgcn_fmed3f(c, bd[k-1], bd[k]);
        }
        bi[0] = m[0] ? j : bi[0];
        bd[0] = fminf(c, bd[0]);
    }
    size_t base = ((size_t)(b * NPTS + i_local) * JCH + jc) * 10;
#pragma unroll
    for (int r = 0; r < 10; ++r) { pd[base + r] = bd[r]; pi_[base + r] = (ushort_t)bi[r]; }
}

// ---------------- KNN phase B: lane-parallel merge, 8 lanes per node ----------------
__global__ __launch_bounds__(256) void knn_merge(const float* __restrict__ pd,
                                                 const ushort_t* __restrict__ pi_,
                                                 int* __restrict__ nbors,
                                                 int* __restrict__ cnt) {
    int tid = blockIdx.x * 256 + threadIdx.x;     // 0..131071
    int node = tid >> 3;                          // 0..16383
    int sub  = tid & 7;                           // list index (jc)
    int b = node >> 10, i = node & 1023;
    int lane = threadIdx.x & 63;

    size_t base = ((size_t)node * JCH + sub) * 10;
    float d[11]; int id[10];
    {
        const float2* dp = (const float2*)(pd + base);
        const unsigned int* ip = (const unsigned int*)(pi_ + base);
#pragma unroll
        for (int q = 0; q < 5; ++q) {
            float2 dv = dp[q];
            unsigned int iv = ip[q];
            d[2*q] = dv.x; d[2*q+1] = dv.y;
            id[2*q] = (int)(iv & 0xffffu); id[2*q+1] = (int)(iv >> 16);
        }
        d[10] = 3.0e38f;
    }

    int res[10];
#pragma unroll
    for (int r = 0; r < 10; ++r) {
        float hd = d[0]; int hl = sub;
#pragma unroll
        for (int mk = 1; mk <= 4; mk <<= 1) {
            float od = __shfl_xor(hd, mk, 64);
            int   ol = __shfl_xor(hl, mk, 64);
            bool take = (od < hd) || (od == hd && ol < hl);
            hd = take ? od : hd;
            hl = take ? ol : hl;
        }
        int src = (lane & 56) | hl;
        res[r] = __shfl(id[0], src, 64);
        bool win = (sub == hl);
#pragma unroll
        for (int k = 0; k < 9; ++k) {
            d[k]  = win ? d[k+1]  : d[k];
            id[k] = win ? id[k+1] : id[k];
        }
        d[9] = win ? d[10] : d[9];
    }

    if (sub == 0) {
        int gi = b * NPTS + i;
#pragma unroll
        for (int r = 0; r < 10; ++r) {
            int gdst = b * NPTS + uclamp(res[r], NPTS - 1);
            nbors[gi * KNN + r] = gdst;
            atomicAdd(&cnt[gdst], 1);
        }
    }
}

// ---------------- reverse-CSR build ----------------
__global__ __launch_bounds__(256) void scan_kernel(const int* __restrict__ cnt,
                                                   int* __restrict__ rs) {
    __shared__ int part[256];
    int t = threadIdx.x;
    int base = t << 6;
    int4 v[16];
    const int4* cp = (const int4*)(cnt + base);
#pragma unroll
    for (int q = 0; q < 16; ++q) v[q] = cp[q];
    int s = 0;
#pragma unroll
    for (int q = 0; q < 16; ++q) s += v[q].x + v[q].y + v[q].z + v[q].w;
    part[t] = s;
    __syncthreads();
    for (int off = 1; off < 256; off <<= 1) {
        int vv = (t >= off) ? part[t - off] : 0;
        __syncthreads();
        part[t] += vv;
        __syncthreads();
    }
    int run = part[t] - s;
    int4* rp = (int4*)(rs + base);
#pragma unroll
    for (int q = 0; q < 16; ++q) {
        int4 o;
        o.x = run; run += v[q].x;
        o.y = run; run += v[q].y;
        o.z = run; run += v[q].z;
        o.w = run; run += v[q].w;
        rp[q] = o;
    }
    if (t == 255) rs[NODES] = run;
}

__global__ __launch_bounds__(256) void fill_kernel(const int* __restrict__ nbors,
                                                   const int* __restrict__ rs,
                                                   int* __restrict__ cur,
                                                   int* __restrict__ esrc) {
    int e = blockIdx.x * 256 + threadIdx.x;
    if (e < EDGES) {
        int dst = uclamp(nbors[e], NODES - 1);
        int src = e / 10;
        int pos = atomicAdd(&cur[dst], 1);
        esrc[uclamp(rs[dst] + pos, EDGES - 1)] = src;
    }
}

// ---------------- layer-0 GEMM (f32 vector, K=16) + fused neighbor-agg, bf16 out -----
__global__ __launch_bounds__(256) void gemm_layer0(const float* __restrict__ A1,
                                                   const int* __restrict__ rs,
                                                   const int* __restrict__ esrc,
                                                   const float* __restrict__ W1,
                                                   const float* __restrict__ W2,
                                                   const float* __restrict__ bias,
                                                   ushort_t* __restrict__ Out,
                                                   int Ndim) {
    __shared__ float As1[16 * 64], As2[16 * 64], Bs1[16 * 64], Bs2[16 * 64];
    int tid = threadIdx.x;
    int m0 = blockIdx.y * 64;
    int n0 = blockIdx.x * 64;
    int tx = tid & 15, ty = tid >> 4;
    int lr = tid >> 2;
    int lc = (tid & 3) << 2;
    float acc[4][4] = {};

    {   // stage x (transposed) and both weight tiles
        float4 a = *(const float4*)(A1 + (size_t)(m0 + lr) * 16 + lc);
        As1[(lc + 0) * 64 + lr] = a.x; As1[(lc + 1) * 64 + lr] = a.y;
        As1[(lc + 2) * 64 + lr] = a.z; As1[(lc + 3) * 64 + lr] = a.w;
        float4 w1 = *(const float4*)(W1 + (size_t)(n0 + lr) * 16 + lc);
        Bs1[(lc + 0) * 64 + lr] = w1.x; Bs1[(lc + 1) * 64 + lr] = w1.y;
        Bs1[(lc + 2) * 64 + lr] = w1.z; Bs1[(lc + 3) * 64 + lr] = w1.w;
        float4 w2 = *(const float4*)(W2 + (size_t)(n0 + lr) * 16 + lc);
        Bs2[(lc + 0) * 64 + lr] = w2.x; Bs2[(lc + 1) * 64 + lr] = w2.y;
        Bs2[(lc + 2) * 64 + lr] = w2.z; Bs2[(lc + 3) * 64 + lr] = w2.w;
    }
    {   // fused agg: 4 threads per row, 4 channels each
        int r = tid >> 2;
        int c4 = (tid & 3) << 2;
        int n = m0 + r;
        int e1 = uclamp(rs[n + 1], EDGES);
        int e0 = uclamp(rs[n], e1);
        float4 acc4 = {0.f, 0.f, 0.f, 0.f};
        for (int e = e0; e < e1; ++e) {
            int s = uclamp(esrc[e], NODES - 1);
            float4 v = *(const float4*)(A1 + (size_t)s * 16 + c4);
            acc4.x += v.x; acc4.y += v.y; acc4.z += v.z; acc4.w += v.w;
        }
        As2[(c4 + 0) * 64 + r] = acc4.x; As2[(c4 + 1) * 64 + r] = acc4.y;
        As2[(c4 + 2) * 64 + r] = acc4.z; As2[(c4 + 3) * 64 + r] = acc4.w;
    }
    __syncthreads();
#pragma unroll
    for (int k = 0; k < 16; ++k) {
        float4 a1 = *(const float4*)(As1 + k * 64 + (ty << 2));
        float4 a2 = *(const float4*)(As2 + k * 64 + (ty << 2));
        float4 b1 = *(const float4*)(Bs1 + k * 64 + (tx << 2));
        float4 b2 = *(const float4*)(Bs2 + k * 64 + (tx << 2));
        float av1[4] = {a1.x, a1.y, a1.z, a1.w};
        float av2[4] = {a2.x, a2.y, a2.z, a2.w};
        float bv1[4] = {b1.x, b1.y, b1.z, b1.w};
        float bv2[4] = {b2.x, b2.y, b2.z, b2.w};
#pragma unroll
        for (int u = 0; u < 4; ++u)
#pragma unroll
            for (int v = 0; v < 4; ++v)
                acc[u][v] += av1[u] * bv1[v] + av2[u] * bv2[v];
    }
    float bv[4];
#pragma unroll
    for (int v = 0; v < 4; ++v) bv[v] = bias[n0 + (tx << 2) + v];
#pragma unroll
    for (int u = 0; u < 4; ++u) {
        int m = m0 + (ty << 2) + u;
        ushort4 o;
        o.x = f2bf(fmaxf(acc[u][0] + bv[0], 0.f));
        o.y = f2bf(fmaxf(acc[u][1] + bv[1], 0.f));
        o.z = f2bf(fmaxf(acc[u][2] + bv[2], 0.f));
        o.w = f2bf(fmaxf(acc[u][3] + bv[3], 0.f));
        *(ushort4*)(Out + (size_t)m * Ndim + n0 + (tx << 2)) = o;
    }
}

// ---------------- aggregation bf16 (layers 1-2), 2-way edge split per node ----------
// sh = log2(threads per node) = log2(din/4). Thread: channel slice (sub & half-1),
// edge parity (sub >> (sh-1)). Partner partials combined via shfl_xor(half).
__global__ __launch_bounds__(256) void agg_bf16(const ushort_t* __restrict__ hin,
                                                ushort_t* __restrict__ agg,
                                                const int* __restrict__ rs,
                                                const int* __restrict__ esrc,
                                                int din, int sh) {
    int gid = blockIdx.x * 256 + threadIdx.x;
    int n = gid >> sh;
    int sub = gid & ((1 << sh) - 1);
    int half = 1 << (sh - 1);
    int c = (sub & (half - 1)) << 3;
    int par = sub >> (sh - 1);
    int e1 = uclamp(rs[n + 1], EDGES);
    int e0 = uclamp(rs[n], e1);
    float a[8] = {0.f,0.f,0.f,0.f,0.f,0.f,0.f,0.f};
    for (int e = e0 + par; e < e1; e += 2) {
        int s = uclamp(esrc[e], NODES - 1);
        u16x8 v = *(const u16x8*)(hin + (size_t)s * din + c);
#pragma unroll
        for (int k = 0; k < 8; ++k) a[k] += bf2f(v[k]);
    }
#pragma unroll
    for (int k = 0; k < 8; ++k) a[k] += __shfl_xor(a[k], half, 64);
    if (par == 0) {
        u16x8 o;
#pragma unroll
        for (int k = 0; k < 8; ++k) o[k] = f2bf(a[k]);
        *(u16x8*)(agg + (size_t)n * din + c) = o;
    }
}

// ---------------- MFMA dual-GEMM with LDS-staged weights (layers 1-2) ----------------
// grid (4, 256) x 256 (4 waves). Block: rows m0..m0+63, cols n0..n0+63.
// W1/W2 64-row tiles staged in LDS (XOR-swizzled) once -> MFMA loop reads weights
// at LDS latency instead of serialized L2/L3 loads (the r6/r7 bottleneck).
template<int KD>
__global__ __launch_bounds__(256) void gemm2(const ushort_t* __restrict__ A1,
                                             const ushort_t* __restrict__ A2,
                                             const ushort_t* __restrict__ W1,
                                             const ushort_t* __restrict__ W2,
                                             const float* __restrict__ bias,
                                             ushort_t* __restrict__ outp) {
    __shared__ ushort_t Ws1[64 * KD], Ws2[64 * KD];   // 2x16KB (KD=128) / 2x32KB (256)
    int tid = threadIdx.x;
    int m0 = blockIdx.y * 64;
    int n0 = blockIdx.x * 64;

    {   // stage weight tiles: coalesced global, swizzled LDS
        constexpr int VPM = 64 * KD / 8;      // u16x8 vectors per matrix
#pragma unroll
        for (int j = 0; j < VPM / 256; ++j) {
            int vi = j * 256 + tid;
            int row = vi / (KD / 8);
            int ch  = (vi % (KD / 8)) * 8;
            u16x8 w1 = *(const u16x8*)(W1 + (size_t)(n0 + row) * KD + ch);
            u16x8 w2 = *(const u16x8*)(W2 + (size_t)(n0 + row) * KD + ch);
            unsigned byte = ((unsigned)(row * KD + ch) * 2u)
                          ^ (((unsigned)(row & 7)) << 4);
            *(u16x8*)((char*)Ws1 + byte) = w1;
            *(u16x8*)((char*)Ws2 + byte) = w2;
        }
    }
    __syncthreads();

    int wave = tid >> 6, lane = tid & 63;
    int quad = lane >> 4, l16 = lane & 15;
    int ms = m0 + wave * 16;

    f32x4 acc[4] = {};
    const ushort_t* a1p = A1 + (size_t)(ms + l16) * KD + quad * 8;
    const ushort_t* a2p = A2 + (size_t)(ms + l16) * KD + quad * 8;

#pragma unroll
    for (int k0 = 0; k0 < KD; k0 += 32) {
        bf16x8 a1 = *(const bf16x8*)(a1p + k0);
        bf16x8 a2 = *(const bf16x8*)(a2p + k0);
#pragma unroll
        for (int nt = 0; nt < 4; ++nt) {
            int row = nt * 16 + l16;
            unsigned byte = ((unsigned)(row * KD + quad * 8 + k0) * 2u)
                          ^ (((unsigned)(row & 7)) << 4);
            bf16x8 u = *(const bf16x8*)((const char*)Ws1 + byte);
            bf16x8 v = *(const bf16x8*)((const char*)Ws2 + byte);
            acc[nt] = __builtin_amdgcn_mfma_f32_16x16x32_bf16(a1, u, acc[nt], 0, 0, 0);
            acc[nt] = __builtin_amdgcn_mfma_f32_16x16x32_bf16(a2, v, acc[nt], 0, 0, 0);
        }
    }
#pragma unroll
    for (int nt = 0; nt < 4; ++nt) {
        int n = n0 + nt * 16 + l16;
        float bb = bias[n];
#pragma unroll
        for (int r = 0; r < 4; ++r) {
            float v = fmaxf(acc[nt][r] + bb, 0.f);
            int m = ms + quad * 4 + r;
            outp[(size_t)m * 256 + n] = f2bf(v);
        }
    }
}

// ---------------- layer-3 GEMM: shared-A dual out, LDS-staged weights ----------------
// N=64, K=256; P=h.Wrel^T, Q=h.Wroot^T both f32 (project first, aggregate after).
__global__ __launch_bounds__(256) void gemm_l3(const ushort_t* __restrict__ A,
                                               const ushort_t* __restrict__ Wroot,
                                               const ushort_t* __restrict__ Wrel,
                                               float* __restrict__ Q3,
                                               float* __restrict__ P3) {
    constexpr int KD = 256;
    __shared__ ushort_t Ws1[64 * KD], Ws2[64 * KD];   // 64 KB
    int tid = threadIdx.x;
    int ms = blockIdx.y * 64 + (tid >> 6) * 16;

    {
        constexpr int VPM = 64 * KD / 8;
#pragma unroll
        for (int j = 0; j < VPM / 256; ++j) {
            int vi = j * 256 + tid;
            int row = vi / (KD / 8);
            int ch  = (vi % (KD / 8)) * 8;
            u16x8 w1 = *(const u16x8*)(Wroot + (size_t)row * KD + ch);
            u16x8 w2 = *(const u16x8*)(Wrel + (size_t)row * KD + ch);
            unsigned byte = ((unsigned)(row * KD + ch) * 2u)
                          ^ (((unsigned)(row & 7)) << 4);
            *(u16x8*)((char*)Ws1 + byte) = w1;
            *(u16x8*)((char*)Ws2 + byte) = w2;
        }
    }
    __syncthreads();

    int lane = tid & 63;
    int quad = lane >> 4, l16 = lane & 15;

    f32x4 accQ[4] = {};
    f32x4 accP[4] = {};
    const ushort_t* ap = A + (size_t)(ms + l16) * KD + quad * 8;

#pragma unroll
    for (int k0 = 0; k0 < KD; k0 += 32) {
        bf16x8 a = *(const bf16x8*)(ap + k0);
#pragma unroll
        for (int nt = 0; nt < 4; ++nt) {
            int row = nt * 16 + l16;
            unsigned byte = ((unsigned)(row * KD + quad * 8 + k0) * 2u)
                          ^ (((unsigned)(row & 7)) << 4);
            bf16x8 u = *(const bf16x8*)((const char*)Ws1 + byte);
            bf16x8 v = *(const bf16x8*)((const char*)Ws2 + byte);
            accQ[nt] = __builtin_amdgcn_mfma_f32_16x16x32_bf16(a, u, accQ[nt], 0, 0, 0);
            accP[nt] = __builtin_amdgcn_mfma_f32_16x16x32_bf16(a, v, accP[nt], 0, 0, 0);
        }
    }
#pragma unroll
    for (int nt = 0; nt < 4; ++nt) {
        int n = nt * 16 + l16;
#pragma unroll
        for (int r = 0; r < 4; ++r) {
            int m = ms + quad * 4 + r;
            Q3[(size_t)m * 64 + n] = accQ[nt][r];
            P3[(size_t)m * 64 + n] = accP[nt][r];
        }
    }
}

// ---------------- layer-3 aggregate + bias + hi/lo split (2-way edge split) ---------
// 32 threads/node: 16 channel-slices x 2 edge parities; shfl_xor(16) combine.
__global__ __launch_bounds__(256) void agg_final(const float* __restrict__ P3,
                                                 const float* __restrict__ Q3,
                                                 const float* __restrict__ bias,
                                                 const int* __restrict__ rs,
                                                 const int* __restrict__ esrc,
                                                 ushort_t* __restrict__ h4hi,
                                                 ushort_t* __restrict__ h4lo) {
    int gid = blockIdx.x * 256 + threadIdx.x;     // 0..524287
    int n = gid >> 5;
    int sub = gid & 31;
    int c = (sub & 15) << 2;
    int par = sub >> 4;
    int e1 = uclamp(rs[n + 1], EDGES);
    int e0 = uclamp(rs[n], e1);
    float4 acc = {0.f, 0.f, 0.f, 0.f};
    for (int e = e0 + par; e < e1; e += 2) {
        int s = uclamp(esrc[e], NODES - 1);
        float4 v = *(const float4*)(P3 + (size_t)s * 64 + c);
        acc.x += v.x; acc.y += v.y; acc.z += v.z; acc.w += v.w;
    }
    acc.x += __shfl_xor(acc.x, 16, 64);
    acc.y += __shfl_xor(acc.y, 16, 64);
    acc.z += __shfl_xor(acc.z, 16, 64);
    acc.w += __shfl_xor(acc.w, 16, 64);
    if (par == 0) {
        float4 q = *(const float4*)(Q3 + (size_t)n * 64 + c);
        float4 bb = *(const float4*)(bias + c);
        float v0 = acc.x + q.x + bb.x;
        float v1 = acc.y + q.y + bb.y;
        float v2 = acc.z + q.z + bb.z;
        float v3 = acc.w + q.w + bb.w;
        ushort4 hi, lo;
        hi.x = f2bf(v0); lo.x = f2bf(v0 - bf2f(hi.x));
        hi.y = f2bf(v1); lo.y = f2bf(v1 - bf2f(hi.y));
        hi.z = f2bf(v2); lo.z = f2bf(v2 - bf2f(hi.z));
        hi.w = f2bf(v3); lo.w = f2bf(v3 - bf2f(hi.w));
        *(ushort4*)(h4hi + (size_t)n * 64 + c) = hi;
        *(ushort4*)(h4lo + (size_t)n * 64 + c) = lo;
    }
}

// ---------------- final Gram via split-bf16 MFMA: D = H·H^T, f32 out ----------------
__global__ __launch_bounds__(256) void final_mfma(const ushort_t* __restrict__ Hhi,
                                                  const ushort_t* __restrict__ Hlo,
                                                  float* __restrict__ out) {
    int tid = threadIdx.x;
    int wave = tid >> 6, lane = tid & 63;
    int quad = lane >> 4, l16 = lane & 15;
    int bz = blockIdx.z;
    int nbase = blockIdx.y * 64 + wave * 16;
    int m0 = blockIdx.x * 64;
    const ushort_t* Hbh = Hhi + (size_t)bz * NPTS * 64;
    const ushort_t* Hbl = Hlo + (size_t)bz * NPTS * 64;

    f32x4 acc[4] = {{0.f,0.f,0.f,0.f},{0.f,0.f,0.f,0.f},{0.f,0.f,0.f,0.f},{0.f,0.f,0.f,0.f}};
    const ushort_t* aph = Hbh + (size_t)(nbase + l16) * 64 + quad * 8;
    const ushort_t* apl = Hbl + (size_t)(nbase + l16) * 64 + quad * 8;
    const ushort_t* bph = Hbh + (size_t)(m0 + l16) * 64 + quad * 8;
    const ushort_t* bpl = Hbl + (size_t)(m0 + l16) * 64 + quad * 8;

#pragma unroll
    for (int k0 = 0; k0 < 64; k0 += 32) {
        bf16x8 ah = *(const bf16x8*)(aph + k0);
        bf16x8 al = *(const bf16x8*)(apl + k0);
#pragma unroll
        for (int nt = 0; nt < 4; ++nt) {
            bf16x8 bh = *(const bf16x8*)(bph + (size_t)nt * 16 * 64 + k0);
            bf16x8 bl = *(const bf16x8*)(bpl + (size_t)nt * 16 * 64 + k0);
            acc[nt] = __builtin_amdgcn_mfma_f32_16x16x32_bf16(ah, bh, acc[nt], 0, 0, 0);
            acc[nt] = __builtin_amdgcn_mfma_f32_16x16x32_bf16(ah, bl, acc[nt], 0, 0, 0);
            acc[nt] = __builtin_amdgcn_mfma_f32_16x16x32_bf16(al, bh, acc[nt], 0, 0, 0);
        }
    }
#pragma unroll
    for (int nt = 0; nt < 4; ++nt) {
#pragma unroll
        for (int r = 0; r < 4; ++r) {
            int n = nbase + quad * 4 + r;
            int m = m0 + nt * 16 + l16;
            out[((size_t)(bz * NPTS + n)) * NPTS + m] = acc[nt][r];
        }
    }
}

// ---------------- launch ----------------
extern "C" void kernel_launch(void* const* d_in, const int* in_sizes, int n_in,
                              void* d_out, int out_size, void* d_ws, size_t ws_size,
                              hipStream_t stream) {
    const float* x = (const float*)d_in[0];
    const float* W[12];
    for (int i = 0; i < 12; ++i) W[i] = (const float*)d_in[1 + i];
    float* out = (float*)d_out;

    // d_ws (~5.5 MB): h4 hi/lo + graph structs
    char* w = (char*)d_ws;
    ushort_t* h4hi = (ushort_t*)w; w += (size_t)NODES * 64 * 2;     // 2 MB
    ushort_t* h4lo = (ushort_t*)w; w += (size_t)NODES * 64 * 2;     // 2 MB
    int* nbors  = (int*)w;    w += (size_t)EDGES * 4;               // 640 KB
    int* cnt    = (int*)w;    w += (size_t)NODES * 4;               // 64 KB
    int* cur    = (int*)w;    w += (size_t)NODES * 4;               // 64 KB (contiguous after cnt)
    int* rs     = (int*)w;    w += (size_t)(NODES + 1) * 4 + 12;    // 64 KB
    int* esrc   = (int*)w;    w += (size_t)EDGES * 4;               // 640 KB

    // scratch inside d_out (64 MB, fully overwritten by final_mfma).
    char* ob = (char*)d_out;
    ushort_t* wb    = (ushort_t*)(ob + 0);                   // 448 KB bf16 weights
    float*    sqh   = (float*)   (ob + (size_t)512*1024);    // 64 KB (0.5*|x|^2)
    float*    pd    = (float*)   (ob + (size_t) 1u*1048576); // 5 MiB [node][jc(8)][10] f32
    ushort_t* pi_   = (ushort_t*)(ob + (size_t) 6u*1048576); // 2.5 MiB
    ushort_t* h1b   = (ushort_t*)(ob + (size_t) 1u*1048576); // 4 MB  (aliases pd)
    ushort_t* h2b   = (ushort_t*)(ob + (size_t)13u*1048576); // 8 MB
    ushort_t* h3b   = (ushort_t*)(ob + (size_t)21u*1048576); // 8 MB
    float*    P3    = (float*)   (ob + (size_t)29u*1048576); // 4 MB f32 (h3.Wrel^T)
    float*    Q3    = (float*)   (ob + (size_t)33u*1048576); // 4 MB f32 (h3.Wroot^T)
    ushort_t* aggb  = (ushort_t*)(ob + (size_t)37u*1048576); // 8 MB bf16 agg

    cast_weights<<<896, 256, 0, stream>>>(W[3], W[4], W[6], W[7], W[9], W[10], wb, x, sqh, cnt);
    knn_partial<<<dim3(JCH, 8, BATCH), 128, 0, stream>>>(x, sqh, pd, pi_);
    knn_merge<<<512, 256, 0, stream>>>(pd, pi_, nbors, cnt);   // fused in-degree count
    scan_kernel<<<1, 256, 0, stream>>>(cnt, rs);
    fill_kernel<<<EDGES / 256, 256, 0, stream>>>(nbors, rs, cur, esrc);

    // layer 0: K=16, N=128, f32 compute, fused neighbor-agg, bf16 out
    gemm_layer0<<<dim3(2, 256), 256, 0, stream>>>(x, rs, esrc, W[0], W[1], W[2], h1b, 128);
    // layer 1: K=128, N=256  (agg: 32 thr/node -> sh=5; gemm: LDS weights)
    agg_bf16<<<NODES * 32 / 256, 256, 0, stream>>>(h1b, aggb, rs, esrc, 128, 5);
    gemm2<128><<<dim3(4, 256), 256, 0, stream>>>(h1b, aggb, wb, wb + 32768, W[5], h2b);
    // layer 2: K=256, N=256  (agg: 64 thr/node -> sh=6)
    agg_bf16<<<NODES * 64 / 256, 256, 0, stream>>>(h2b, aggb, rs, esrc, 256, 6);
    gemm2<256><<<dim3(4, 256), 256, 0, stream>>>(h2b, aggb, wb + 65536, wb + 131072,
                                                 W[8], h3b);
    // layer 3: project first (LDS weights), then aggregate 64-dim rows
    gemm_l3<<<dim3(1, 256), 256, 0, stream>>>(h3b, wb + 196608, wb + 212992, Q3, P3);
    agg_final<<<NODES * 32 / 256, 256, 0, stream>>>(P3, Q3, W[11], rs, esrc, h4hi, h4lo);

    final_mfma<<<dim3(16, 16, 16), 256, 0, stream>>>(h4hi, h4lo, out);
}